// Round 2
// baseline (708.531 us; speedup 1.0000x reference)
//
#include <hip/hip_runtime.h>
#include <math.h>

#define IN_CH 13
#define HIDDEN 20
#define NCLS 10
#define NBASIS 8
#define NGRID 12
#define NTHREADS 256

typedef unsigned short u16;
typedef unsigned int u32;

__device__ inline float bf2f(u16 u) {
    union { u32 i; float f; } v; v.i = ((u32)u) << 16; return v.f;
}
__device__ inline u16 f2bf(float f) {
    union { float f; u32 i; } v; v.f = f;
    u32 x = v.i;
    return (u16)((x + 0x7fffu + ((x >> 16) & 1u)) >> 16);
}
// load parameter element idx from p, fp32 or bf16 per flag
__device__ inline float ldp(const void* __restrict__ p, int idx, int isf32) {
    return isf32 ? ((const float*)p)[idx] : bf2f(((const u16*)p)[idx]);
}

// --- dtype detector: fp32 normals ~always in (1e-6,1e4); bf16-pair bit
// patterns read as fp32 are ~always 1e38-ish or NaN. Writes 1 if fp32. ---
__global__ void detect_dtype(const u32* __restrict__ x, int* __restrict__ flag) {
    if (threadIdx.x == 0 && blockIdx.x == 0) {
        int cnt = 0;
        for (int i = 0; i < 256; ++i) {
            union { u32 i; float f; } v; v.i = x[i];
            float a = fabsf(v.f);
            if (a > 1e-6f && a < 1e4f) cnt++;
        }
        flag[0] = (cnt >= 192) ? 1 : 0;
    }
}

// depthwise 3x3 stride-2 pad-1 conv over a square LDS image, relu epilogue
__device__ inline void dwconv3(const float* __restrict__ in, float* __restrict__ out,
                               int inW, int outW, const float* __restrict__ w,
                               float bias, int tid) {
    int n = outW * outW;
    for (int o = tid; o < n; o += NTHREADS) {
        int oy = o / outW, ox = o - oy * outW;
        float acc = bias;
        #pragma unroll
        for (int ky = 0; ky < 3; ++ky) {
            int iy = 2 * oy - 1 + ky;
            if (iy < 0 || iy >= inW) continue;
            #pragma unroll
            for (int kx = 0; kx < 3; ++kx) {
                int ix = 2 * ox - 1 + kx;
                if (ix < 0 || ix >= inW) continue;
                acc += w[ky * 3 + kx] * in[iy * inW + ix];
            }
        }
        out[o] = fmaxf(acc, 0.0f);
    }
}

__global__ __launch_bounds__(NTHREADS) void conv_pipeline(
    const void* __restrict__ x,
    const void* __restrict__ w1, const void* __restrict__ b1,
    const void* __restrict__ w2, const void* __restrict__ b2,
    const void* __restrict__ w3, const void* __restrict__ b3,
    const void* __restrict__ w4, const void* __restrict__ b4,
    const void* __restrict__ w5, const void* __restrict__ b5,
    const void* __restrict__ w6, const void* __restrict__ b6,
    const int* __restrict__ flag,
    float* __restrict__ h)
{
    __shared__ float sA[64 * 64];
    __shared__ float sB[32 * 32];
    __shared__ float sw[49];
    __shared__ float sbias[6];

    int tid = threadIdx.x;
    int bc = blockIdx.x;              // b*13 + c
    int c = bc % IN_CH;
    int isf32 = flag[0];

    if (tid < 9) {
        sw[tid]      = ldp(w1, c * 9 + tid, isf32);
        sw[9 + tid]  = ldp(w2, c * 9 + tid, isf32);
        sw[18 + tid] = ldp(w3, c * 9 + tid, isf32);
        sw[27 + tid] = ldp(w4, c * 9 + tid, isf32);
        sw[36 + tid] = ldp(w5, c * 9 + tid, isf32);
    }
    if (tid < 4) sw[45 + tid] = ldp(w6, c * 4 + tid, isf32);
    if (tid == 0) {
        sbias[0] = ldp(b1, c, isf32); sbias[1] = ldp(b2, c, isf32);
        sbias[2] = ldp(b3, c, isf32); sbias[3] = ldp(b4, c, isf32);
        sbias[4] = ldp(b5, c, isf32); sbias[5] = ldp(b6, c, isf32);
    }

    if (isf32) {
        const float4* xv = reinterpret_cast<const float4*>((const float*)x + (size_t)bc * 4096);
        #pragma unroll
        for (int i = 0; i < 4; ++i) {
            int v = tid + i * NTHREADS;   // 0..1023 vec slots of 4 floats
            float4 u = xv[v];
            int base = v * 4;
            sA[base + 0] = u.x; sA[base + 1] = u.y;
            sA[base + 2] = u.z; sA[base + 3] = u.w;
        }
    } else {
        const uint4* xv = reinterpret_cast<const uint4*>((const u16*)x + (size_t)bc * 4096);
        #pragma unroll
        for (int i = 0; i < 2; ++i) {
            int v = tid + i * NTHREADS;   // 0..511 vec slots of 8 bf16
            uint4 u = xv[v];
            int base = v * 8;
            sA[base + 0] = bf2f((u16)(u.x & 0xffff)); sA[base + 1] = bf2f((u16)(u.x >> 16));
            sA[base + 2] = bf2f((u16)(u.y & 0xffff)); sA[base + 3] = bf2f((u16)(u.y >> 16));
            sA[base + 4] = bf2f((u16)(u.z & 0xffff)); sA[base + 5] = bf2f((u16)(u.z >> 16));
            sA[base + 6] = bf2f((u16)(u.w & 0xffff)); sA[base + 7] = bf2f((u16)(u.w >> 16));
        }
    }
    __syncthreads();

    dwconv3(sA, sB, 64, 32, sw,      sbias[0], tid); __syncthreads();
    dwconv3(sB, sA, 32, 16, sw + 9,  sbias[1], tid); __syncthreads();
    dwconv3(sA, sB, 16,  8, sw + 18, sbias[2], tid); __syncthreads();
    dwconv3(sB, sA,  8,  4, sw + 27, sbias[3], tid); __syncthreads();
    dwconv3(sA, sB,  4,  2, sw + 36, sbias[4], tid); __syncthreads();

    if (tid == 0) {
        // conv6: 2x2 kernel, stride 1, no pad, no relu
        float acc = sbias[5]
                  + sw[45] * sB[0] + sw[46] * sB[1]
                  + sw[47] * sB[2] + sw[48] * sB[3];
        h[bc] = acc;
    }
}

__global__ __launch_bounds__(NTHREADS) void kan_head(
    const float* __restrict__ h,
    const void* __restrict__ grid1, const void* __restrict__ coef1,
    const void* __restrict__ sb1,   const void* __restrict__ ss1,
    const void* __restrict__ bias1,
    const void* __restrict__ grid2, const void* __restrict__ coef2,
    const void* __restrict__ sb2,   const void* __restrict__ ss2,
    const void* __restrict__ bias2,
    const int* __restrict__ flag,
    void* __restrict__ out, int nsamples)
{
    __shared__ float sg1[IN_CH * NGRID];
    __shared__ float sc1[IN_CH * HIDDEN * NBASIS];
    __shared__ float ssb1[IN_CH * HIDDEN];
    __shared__ float sss1[IN_CH * HIDDEN];
    __shared__ float sbias1[HIDDEN];
    __shared__ float sg2[HIDDEN * NGRID];
    __shared__ float sc2[HIDDEN * NCLS * NBASIS];
    __shared__ float ssb2[HIDDEN * NCLS];
    __shared__ float sss2[HIDDEN * NCLS];
    __shared__ float sbias2[NCLS];

    int tid = threadIdx.x;
    int isf32 = flag[0];
    for (int i = tid; i < IN_CH * NGRID; i += NTHREADS)           sg1[i] = ldp(grid1, i, isf32);
    for (int i = tid; i < IN_CH * HIDDEN * NBASIS; i += NTHREADS) sc1[i] = ldp(coef1, i, isf32);
    for (int i = tid; i < IN_CH * HIDDEN; i += NTHREADS)          ssb1[i] = ldp(sb1, i, isf32);
    for (int i = tid; i < IN_CH * HIDDEN; i += NTHREADS)          sss1[i] = ldp(ss1, i, isf32);
    for (int i = tid; i < HIDDEN; i += NTHREADS)                  sbias1[i] = ldp(bias1, i, isf32);
    for (int i = tid; i < HIDDEN * NGRID; i += NTHREADS)          sg2[i] = ldp(grid2, i, isf32);
    for (int i = tid; i < HIDDEN * NCLS * NBASIS; i += NTHREADS)  sc2[i] = ldp(coef2, i, isf32);
    for (int i = tid; i < HIDDEN * NCLS; i += NTHREADS)           ssb2[i] = ldp(sb2, i, isf32);
    for (int i = tid; i < HIDDEN * NCLS; i += NTHREADS)           sss2[i] = ldp(ss2, i, isf32);
    for (int i = tid; i < NCLS; i += NTHREADS)                    sbias2[i] = ldp(bias2, i, isf32);
    __syncthreads();

    int s = blockIdx.x * NTHREADS + tid;
    if (s >= nsamples) return;

    // ---- KAN layer 1: 13 -> 20 ----
    float a2[HIDDEN];
    #pragma unroll
    for (int o = 0; o < HIDDEN; ++o) a2[o] = sbias1[o];

    for (int i = 0; i < IN_CH; ++i) {
        float xv = h[s * IN_CH + i];
        float base = xv / (1.0f + expf(-xv));   // silu
        const float* g = sg1 + i * NGRID;
        float bsp[NGRID - 1];
        #pragma unroll
        for (int j = 0; j < NGRID - 1; ++j)
            bsp[j] = (xv >= g[j] && xv < g[j + 1]) ? 1.0f : 0.0f;
        #pragma unroll
        for (int p = 1; p <= 3; ++p) {
            for (int j = 0; j < NGRID - 1 - p; ++j) {
                float left  = (xv - g[j]) / (g[j + p] - g[j]);
                float right = (g[j + p + 1] - xv) / (g[j + p + 1] - g[j + 1]);
                bsp[j] = left * bsp[j] + right * bsp[j + 1];
            }
        }
        #pragma unroll
        for (int o = 0; o < HIDDEN; ++o) {
            const float* cf = sc1 + (i * HIDDEN + o) * NBASIS;
            float sp = 0.0f;
            #pragma unroll
            for (int n = 0; n < NBASIS; ++n) sp += bsp[n] * cf[n];
            a2[o] += base * ssb1[i * HIDDEN + o] + sp * sss1[i * HIDDEN + o];
        }
    }

    // ---- KAN layer 2: 20 -> 10 ----
    float z[NCLS];
    #pragma unroll
    for (int o = 0; o < NCLS; ++o) z[o] = sbias2[o];

    for (int i = 0; i < HIDDEN; ++i) {
        float xv = a2[i];
        float base = xv / (1.0f + expf(-xv));
        const float* g = sg2 + i * NGRID;
        float bsp[NGRID - 1];
        #pragma unroll
        for (int j = 0; j < NGRID - 1; ++j)
            bsp[j] = (xv >= g[j] && xv < g[j + 1]) ? 1.0f : 0.0f;
        #pragma unroll
        for (int p = 1; p <= 3; ++p) {
            for (int j = 0; j < NGRID - 1 - p; ++j) {
                float left  = (xv - g[j]) / (g[j + p] - g[j]);
                float right = (g[j + p + 1] - xv) / (g[j + p + 1] - g[j + 1]);
                bsp[j] = left * bsp[j] + right * bsp[j + 1];
            }
        }
        #pragma unroll
        for (int o = 0; o < NCLS; ++o) {
            const float* cf = sc2 + (i * NCLS + o) * NBASIS;
            float sp = 0.0f;
            #pragma unroll
            for (int n = 0; n < NBASIS; ++n) sp += bsp[n] * cf[n];
            z[o] += base * ssb2[i * NCLS + o] + sp * sss2[i * NCLS + o];
        }
    }

    // ---- log_softmax ----
    float m = z[0];
    #pragma unroll
    for (int o = 1; o < NCLS; ++o) m = fmaxf(m, z[o]);
    float sum = 0.0f;
    #pragma unroll
    for (int o = 0; o < NCLS; ++o) sum += expf(z[o] - m);
    float lse = logf(sum) + m;

    if (isf32) {
        float* op = (float*)out;
        #pragma unroll
        for (int o = 0; o < NCLS; ++o) op[s * NCLS + o] = z[o] - lse;
    } else {
        u16* op = (u16*)out;
        #pragma unroll
        for (int o = 0; o < NCLS; ++o) op[s * NCLS + o] = f2bf(z[o] - lse);
    }
}

extern "C" void kernel_launch(void* const* d_in, const int* in_sizes, int n_in,
                              void* d_out, int out_size, void* d_ws, size_t ws_size,
                              hipStream_t stream) {
    const void* x  = d_in[0];
    const void* w1 = d_in[1];  const void* b1 = d_in[2];
    const void* w2 = d_in[3];  const void* b2 = d_in[4];
    const void* w3 = d_in[5];  const void* b3 = d_in[6];
    const void* w4 = d_in[7];  const void* b4 = d_in[8];
    const void* w5 = d_in[9];  const void* b5 = d_in[10];
    const void* w6 = d_in[11]; const void* b6 = d_in[12];
    const void* grid1 = d_in[13];
    const void* coef1 = d_in[14];
    const void* sb1   = d_in[15];
    const void* ss1   = d_in[16];
    const void* bias1 = d_in[17];
    const void* grid2 = d_in[18];
    const void* coef2 = d_in[19];
    const void* sb2   = d_in[20];
    const void* ss2   = d_in[21];
    const void* bias2 = d_in[22];

    int B = in_sizes[0] / (IN_CH * 64 * 64);     // 2048 (dtype-independent)
    int* flag = (int*)d_ws;
    float* h = (float*)((char*)d_ws + 16);       // B*IN_CH fp32

    detect_dtype<<<1, 64, 0, stream>>>((const u32*)x, flag);

    conv_pipeline<<<B * IN_CH, NTHREADS, 0, stream>>>(
        x, w1, b1, w2, b2, w3, b3, w4, b4, w5, b5, w6, b6, flag, h);

    kan_head<<<(B + NTHREADS - 1) / NTHREADS, NTHREADS, 0, stream>>>(
        h, grid1, coef1, sb1, ss1, bias1, grid2, coef2, sb2, ss2, bias2,
        flag, d_out, B);
}

// Round 4
// 681.825 us; speedup vs baseline: 1.0392x; 1.0392x over previous
//
#include <hip/hip_runtime.h>
#include <math.h>

#define IN_CH 13
#define HIDDEN 20
#define NCLS 10
#define NBASIS 8
#define NGRID 12
#define NTHREADS 256
#define KAN_NT 64

// All inputs/outputs are fp32 (verified round 2: fp32 path passed absmax=0.0;
// bf16 interpretation NaNs because fp32 low halfwords have random exponents).

// depthwise 3x3 stride-2 pad-1 conv, compile-time sizes, relu epilogue
template<int IW, int OW>
__device__ inline void dwconv3t(const float* __restrict__ in, float* __restrict__ out,
                                const float* __restrict__ w, float bias, int tid) {
    constexpr int N = OW * OW;
    constexpr int ITER = (N + NTHREADS - 1) / NTHREADS;
    #pragma unroll
    for (int r = 0; r < ITER; ++r) {
        int o = tid + r * NTHREADS;
        if (N >= NTHREADS || o < N) {
            int oy = o / OW, ox = o % OW;      // OW pow2 -> shifts/masks
            float acc = bias;
            #pragma unroll
            for (int ky = 0; ky < 3; ++ky) {
                int iy = 2 * oy - 1 + ky;
                bool yok = (iy >= 0) && (iy < IW);
                #pragma unroll
                for (int kx = 0; kx < 3; ++kx) {
                    int ix = 2 * ox - 1 + kx;
                    bool ok = yok && (ix >= 0) && (ix < IW);
                    float v = ok ? in[iy * IW + ix] : 0.0f;
                    acc += w[ky * 3 + kx] * v;
                }
            }
            out[o] = fmaxf(acc, 0.0f);
        }
    }
}

__global__ __launch_bounds__(NTHREADS) void conv_pipeline(
    const float* __restrict__ x,
    const float* __restrict__ w1, const float* __restrict__ b1,
    const float* __restrict__ w2, const float* __restrict__ b2,
    const float* __restrict__ w3, const float* __restrict__ b3,
    const float* __restrict__ w4, const float* __restrict__ b4,
    const float* __restrict__ w5, const float* __restrict__ b5,
    const float* __restrict__ w6, const float* __restrict__ b6,
    float* __restrict__ h)
{
    __shared__ float sA[64 * 64];
    __shared__ float sB[32 * 32];
    __shared__ float sw[49];
    __shared__ float sbias[6];

    int tid = threadIdx.x;
    int bc = blockIdx.x;              // b*13 + c
    int c = bc % IN_CH;

    if (tid < 9) {
        sw[tid]      = w1[c * 9 + tid];
        sw[9 + tid]  = w2[c * 9 + tid];
        sw[18 + tid] = w3[c * 9 + tid];
        sw[27 + tid] = w4[c * 9 + tid];
        sw[36 + tid] = w5[c * 9 + tid];
    }
    if (tid < 4) sw[45 + tid] = w6[c * 4 + tid];
    if (tid == 0) {
        sbias[0] = b1[c]; sbias[1] = b2[c]; sbias[2] = b3[c];
        sbias[3] = b4[c]; sbias[4] = b5[c]; sbias[5] = b6[c];
    }

    // stage 64x64 fp32 tile -> LDS; 16B global loads, 16B LDS stores
    const float4* xv = reinterpret_cast<const float4*>(x + (size_t)bc * 4096);
    float4* sAv = reinterpret_cast<float4*>(sA);
    #pragma unroll
    for (int i = 0; i < 4; ++i) {
        int v = tid + i * NTHREADS;   // 0..1023 float4 slots
        sAv[v] = xv[v];
    }
    __syncthreads();

    dwconv3t<64, 32>(sA, sB, sw,      sbias[0], tid); __syncthreads();
    dwconv3t<32, 16>(sB, sA, sw + 9,  sbias[1], tid); __syncthreads();
    dwconv3t<16,  8>(sA, sB, sw + 18, sbias[2], tid); __syncthreads();
    dwconv3t< 8,  4>(sB, sA, sw + 27, sbias[3], tid); __syncthreads();
    dwconv3t< 4,  2>(sA, sB, sw + 36, sbias[4], tid); __syncthreads();

    if (tid == 0) {
        // conv6: 2x2 kernel, stride 1, no pad, no relu
        float acc = sbias[5]
                  + sw[45] * sB[0] + sw[46] * sB[1]
                  + sw[47] * sB[2] + sw[48] * sB[3];
        h[bc] = acc;
    }
}

__global__ __launch_bounds__(KAN_NT) void kan_head(
    const float* __restrict__ h,
    const float* __restrict__ grid1, const float* __restrict__ coef1,
    const float* __restrict__ sb1,   const float* __restrict__ ss1,
    const float* __restrict__ bias1,
    const float* __restrict__ grid2, const float* __restrict__ coef2,
    const float* __restrict__ sb2,   const float* __restrict__ ss2,
    const float* __restrict__ bias2,
    float* __restrict__ out, int nsamples)
{
    __shared__ float sg1[IN_CH * NGRID];
    __shared__ float sc1[IN_CH * HIDDEN * NBASIS];
    __shared__ float ssb1[IN_CH * HIDDEN];
    __shared__ float sss1[IN_CH * HIDDEN];
    __shared__ float sbias1[HIDDEN];
    __shared__ float sg2[HIDDEN * NGRID];
    __shared__ float sc2[HIDDEN * NCLS * NBASIS];
    __shared__ float ssb2[HIDDEN * NCLS];
    __shared__ float sss2[HIDDEN * NCLS];
    __shared__ float sbias2[NCLS];

    int tid = threadIdx.x;
    for (int i = tid; i < IN_CH * NGRID; i += KAN_NT)           sg1[i] = grid1[i];
    for (int i = tid; i < IN_CH * HIDDEN * NBASIS; i += KAN_NT) sc1[i] = coef1[i];
    for (int i = tid; i < IN_CH * HIDDEN; i += KAN_NT)          ssb1[i] = sb1[i];
    for (int i = tid; i < IN_CH * HIDDEN; i += KAN_NT)          sss1[i] = ss1[i];
    for (int i = tid; i < HIDDEN; i += KAN_NT)                  sbias1[i] = bias1[i];
    for (int i = tid; i < HIDDEN * NGRID; i += KAN_NT)          sg2[i] = grid2[i];
    for (int i = tid; i < HIDDEN * NCLS * NBASIS; i += KAN_NT)  sc2[i] = coef2[i];
    for (int i = tid; i < HIDDEN * NCLS; i += KAN_NT)           ssb2[i] = sb2[i];
    for (int i = tid; i < HIDDEN * NCLS; i += KAN_NT)           sss2[i] = ss2[i];
    for (int i = tid; i < NCLS; i += KAN_NT)                    sbias2[i] = bias2[i];
    __syncthreads();

    int s = blockIdx.x * KAN_NT + tid;
    if (s >= nsamples) return;

    // ---- KAN layer 1: 13 -> 20 ----
    float a2[HIDDEN];
    #pragma unroll
    for (int o = 0; o < HIDDEN; ++o) a2[o] = sbias1[o];

    for (int i = 0; i < IN_CH; ++i) {
        float xv = h[s * IN_CH + i];
        float base = xv / (1.0f + expf(-xv));   // silu
        const float* g = sg1 + i * NGRID;
        float bsp[NGRID - 1];
        #pragma unroll
        for (int j = 0; j < NGRID - 1; ++j)
            bsp[j] = (xv >= g[j] && xv < g[j + 1]) ? 1.0f : 0.0f;
        #pragma unroll
        for (int p = 1; p <= 3; ++p) {
            for (int j = 0; j < NGRID - 1 - p; ++j) {
                float left  = (xv - g[j]) / (g[j + p] - g[j]);
                float right = (g[j + p + 1] - xv) / (g[j + p + 1] - g[j + 1]);
                bsp[j] = left * bsp[j] + right * bsp[j + 1];
            }
        }
        #pragma unroll
        for (int o = 0; o < HIDDEN; ++o) {
            const float* cf = sc1 + (i * HIDDEN + o) * NBASIS;
            float sp = 0.0f;
            #pragma unroll
            for (int n = 0; n < NBASIS; ++n) sp += bsp[n] * cf[n];
            a2[o] += base * ssb1[i * HIDDEN + o] + sp * sss1[i * HIDDEN + o];
        }
    }

    // ---- KAN layer 2: 20 -> 10 ----
    float z[NCLS];
    #pragma unroll
    for (int o = 0; o < NCLS; ++o) z[o] = sbias2[o];

    for (int i = 0; i < HIDDEN; ++i) {
        float xv = a2[i];
        float base = xv / (1.0f + expf(-xv));
        const float* g = sg2 + i * NGRID;
        float bsp[NGRID - 1];
        #pragma unroll
        for (int j = 0; j < NGRID - 1; ++j)
            bsp[j] = (xv >= g[j] && xv < g[j + 1]) ? 1.0f : 0.0f;
        #pragma unroll
        for (int p = 1; p <= 3; ++p) {
            for (int j = 0; j < NGRID - 1 - p; ++j) {
                float left  = (xv - g[j]) / (g[j + p] - g[j]);
                float right = (g[j + p + 1] - xv) / (g[j + p + 1] - g[j + 1]);
                bsp[j] = left * bsp[j] + right * bsp[j + 1];
            }
        }
        #pragma unroll
        for (int o = 0; o < NCLS; ++o) {
            const float* cf = sc2 + (i * NCLS + o) * NBASIS;
            float sp = 0.0f;
            #pragma unroll
            for (int n = 0; n < NBASIS; ++n) sp += bsp[n] * cf[n];
            z[o] += base * ssb2[i * NCLS + o] + sp * sss2[i * NCLS + o];
        }
    }

    // ---- log_softmax ----
    float m = z[0];
    #pragma unroll
    for (int o = 1; o < NCLS; ++o) m = fmaxf(m, z[o]);
    float sum = 0.0f;
    #pragma unroll
    for (int o = 0; o < NCLS; ++o) sum += expf(z[o] - m);
    float lse = logf(sum) + m;
    #pragma unroll
    for (int o = 0; o < NCLS; ++o) out[s * NCLS + o] = z[o] - lse;
}

extern "C" void kernel_launch(void* const* d_in, const int* in_sizes, int n_in,
                              void* d_out, int out_size, void* d_ws, size_t ws_size,
                              hipStream_t stream) {
    const float* x  = (const float*)d_in[0];
    const float* w1 = (const float*)d_in[1];  const float* b1 = (const float*)d_in[2];
    const float* w2 = (const float*)d_in[3];  const float* b2 = (const float*)d_in[4];
    const float* w3 = (const float*)d_in[5];  const float* b3 = (const float*)d_in[6];
    const float* w4 = (const float*)d_in[7];  const float* b4 = (const float*)d_in[8];
    const float* w5 = (const float*)d_in[9];  const float* b5 = (const float*)d_in[10];
    const float* w6 = (const float*)d_in[11]; const float* b6 = (const float*)d_in[12];
    const float* grid1 = (const float*)d_in[13];
    const float* coef1 = (const float*)d_in[14];
    const float* sb1   = (const float*)d_in[15];
    const float* ss1   = (const float*)d_in[16];
    const float* bias1 = (const float*)d_in[17];
    const float* grid2 = (const float*)d_in[18];
    const float* coef2 = (const float*)d_in[19];
    const float* sb2   = (const float*)d_in[20];
    const float* ss2   = (const float*)d_in[21];
    const float* bias2 = (const float*)d_in[22];

    int B = in_sizes[0] / (IN_CH * 64 * 64);     // 2048
    float* h = (float*)d_ws;                      // B*IN_CH fp32

    conv_pipeline<<<B * IN_CH, NTHREADS, 0, stream>>>(
        x, w1, b1, w2, b2, w3, b3, w4, b4, w5, b5, w6, b6, h);

    kan_head<<<(B + KAN_NT - 1) / KAN_NT, KAN_NT, 0, stream>>>(
        h, grid1, coef1, sb1, ss1, bias1, grid2, coef2, sb2, ss2, bias2,
        (float*)d_out, B);
}